// Round 1
// baseline (1109.952 us; speedup 1.0000x reference)
//
#include <hip/hip_runtime.h>
#include <hip/hip_bf16.h>

#define NTOK 8192
#define DDIM 1024
#define HDIM 4096
#define NEXP 8
#define NPAIR (NTOK * 2)

typedef __attribute__((ext_vector_type(8))) short short8;
typedef __attribute__((ext_vector_type(4))) float floatx4;

__device__ __forceinline__ unsigned short f2bf(float f) {
  unsigned u = __float_as_uint(f);
  u += 0x7fffu + ((u >> 16) & 1u);   // RNE
  return (unsigned short)(u >> 16);
}

__device__ __forceinline__ void async_copy16(const void* g, void* l) {
  __builtin_amdgcn_global_load_lds(
      (const __attribute__((address_space(1))) unsigned int*)g,
      (__attribute__((address_space(3))) unsigned int*)l, 16, 0, 0);
}

// ---------------- cast f32 -> bf16, float4 vectorized ----------------
__global__ void cast_kernel(const float* __restrict__ src,
                            unsigned short* __restrict__ dst, int n4) {
  int i = blockIdx.x * 256 + threadIdx.x;
  if (i >= n4) return;
  const float4 v = ((const float4*)src)[i];
  ushort4 o;
  o.x = f2bf(v.x); o.y = f2bf(v.y); o.z = f2bf(v.z); o.w = f2bf(v.w);
  ((ushort4*)dst)[i] = o;
}

// ---------------- gating: 1 wave per token, fp64 accumulation ----------------
__global__ __launch_bounds__(256) void gating_kernel(
    const float* __restrict__ x, const float* __restrict__ gw,
    int* __restrict__ selE, float* __restrict__ selW,
    int* __restrict__ cnt, float* __restrict__ psum) {
  __shared__ float gws[NEXP * DDIM];      // 32 KB
  __shared__ float pblk[4][NEXP];
  __shared__ int cblk[NEXP];
  const int t = threadIdx.x;
  for (int i = t; i < NEXP * DDIM; i += 256) gws[i] = gw[i];
  if (t < NEXP) cblk[t] = 0;
  __syncthreads();
  const int wv = t >> 6, lane = t & 63;
  const int tok = blockIdx.x * 4 + wv;
  double acc[NEXP];
#pragma unroll
  for (int e = 0; e < NEXP; e++) acc[e] = 0.0;
  const float* xr = x + (size_t)tok * DDIM;
  for (int i = lane; i < DDIM; i += 64) {
    double xv = (double)xr[i];
#pragma unroll
    for (int e = 0; e < NEXP; e++) acc[e] += xv * (double)gws[e * DDIM + i];
  }
#pragma unroll
  for (int e = 0; e < NEXP; e++)
    for (int off = 32; off > 0; off >>= 1) acc[e] += __shfl_xor(acc[e], off, 64);
  if (lane == 0) {
    double mx = acc[0];
    for (int e = 1; e < NEXP; e++) mx = acc[e] > mx ? acc[e] : mx;
    double p[NEXP], s = 0.0;
    for (int e = 0; e < NEXP; e++) { p[e] = exp(acc[e] - mx); s += p[e]; }
    int e1 = 0; double b1 = p[0];
    for (int e = 1; e < NEXP; e++) if (p[e] > b1) { b1 = p[e]; e1 = e; }
    int e2 = -1; double b2 = -1.0;
    for (int e = 0; e < NEXP; e++) if (e != e1 && p[e] > b2) { b2 = p[e]; e2 = e; }
    double rs = b1 + b2;
    selE[tok * 2 + 0] = e1; selE[tok * 2 + 1] = e2;
    selW[tok * 2 + 0] = (float)(b1 / rs); selW[tok * 2 + 1] = (float)(b2 / rs);
    atomicAdd(&cblk[e1], 1); atomicAdd(&cblk[e2], 1);
    for (int e = 0; e < NEXP; e++) pblk[wv][e] = (float)(p[e] / s);
  }
  __syncthreads();
  if (t < NEXP) {
    float sp = pblk[0][t] + pblk[1][t] + pblk[2][t] + pblk[3][t];
    atomicAdd(&psum[t], sp);
    if (cblk[t]) atomicAdd(&cnt[t], cblk[t]);
  }
}

// ---------------- prefix sum over 8 experts + balance loss ----------------
__global__ void finalize_kernel(const int* __restrict__ cnt,
                                const float* __restrict__ psum,
                                int* __restrict__ base, int* __restrict__ fill,
                                float* __restrict__ loss_out) {
  int b = 0;
  for (int e = 0; e < NEXP; e++) { base[e] = b; fill[e] = b; b += cnt[e]; }
  base[NEXP] = b;
  double L = 0.0;
  for (int e = 0; e < NEXP; e++) L += (double)psum[e] * (double)cnt[e];
  *loss_out = (float)(L * (double)NEXP / ((double)NTOK * (double)NTOK));
}

// ---------------- scatter (token, weight) pairs into compact per-expert lists ----------------
__global__ void scatter_kernel(const int* __restrict__ selE,
                               const float* __restrict__ selW,
                               int* __restrict__ fill, int* __restrict__ pairtok,
                               float* __restrict__ pairw) {
  int n = blockIdx.x * 256 + threadIdx.x;
  if (n >= NTOK) return;
  for (int k = 0; k < 2; k++) {
    int e = selE[n * 2 + k];
    int pos = atomicAdd(&fill[e], 1);
    pairtok[pos] = n;
    pairw[pos] = selW[n * 2 + k];
  }
}

// ---------------- MFMA GEMM, NT layout (A [M][K], B [N][K] both K-major) ----------------
// MODE 0: FC1  A = xb gathered via pairtok, epilogue relu^2 -> hbuf bf16
// MODE 1: FC2  A = hbuf compact rows,       epilogue atomicAdd(out[tok], w*y)
template <int KD, int ND, int MODE>
__global__ __launch_bounds__(256) void moe_gemm(
    const unsigned short* __restrict__ A, const unsigned short* __restrict__ B,
    const int* __restrict__ base, const int* __restrict__ pairtok,
    const float* __restrict__ pairw, unsigned short* __restrict__ hbuf,
    float* __restrict__ out) {
  const int e = blockIdx.z;
  const int m0 = base[e], m1 = base[e + 1];
  const int cntE = m1 - m0;
  const int mtile = blockIdx.x;
  if (mtile * 128 >= cntE) return;
  const int ntile = blockIdx.y;

  __shared__ unsigned short ldsA[512 * 8];   // 128 x 32 bf16, 16B-chunk xor-swizzled
  __shared__ unsigned short ldsB[512 * 8];

  const int t = threadIdx.x, w = t >> 6, lane = t & 63;

  // staging: chunk c = wavebase + lane; chunk holds (row=c>>2, q=(c&3)^swz(row))
  const unsigned short* gA[2];
  const unsigned short* gB[2];
  unsigned short* dstA[2];
  unsigned short* dstB[2];
#pragma unroll
  for (int i = 0; i < 2; i++) {
    const int c = w * 128 + i * 64 + lane;
    const int row = c >> 2;
    const int q = (c & 3) ^ (row & 3) ^ ((row >> 2) & 3);
    dstA[i] = ldsA + (w * 128 + i * 64) * 8;   // wave-uniform LDS base
    dstB[i] = ldsB + (w * 128 + i * 64) * 8;
    int ar = mtile * 128 + row;
    if (ar > cntE - 1) ar = cntE - 1;          // clamp tail rows
    size_t arow;
    if (MODE == 0) arow = (size_t)pairtok[m0 + ar];
    else           arow = (size_t)(m0 + ar);
    gA[i] = A + arow * (size_t)KD + q * 8;
    gB[i] = B + ((size_t)e * ND + (ntile * 128 + row)) * (size_t)KD + q * 8;
  }

  // fragment read addresses (fixed across K loop)
  const int wm = (w & 1) * 64, wn = (w >> 1) * 64;
  const int sw = (lane >> 4) ^ (lane & 3) ^ ((lane >> 2) & 3);
  const short8* aptr[4];
  const short8* bptr[4];
#pragma unroll
  for (int i = 0; i < 4; i++) {
    aptr[i] = (const short8*)ldsA + (wm + i * 16 + (lane & 15)) * 4 + sw;
    bptr[i] = (const short8*)ldsB + (wn + i * 16 + (lane & 15)) * 4 + sw;
  }

  floatx4 acc[4][4] = {};

  for (int kt = 0; kt < KD / 32; kt++) {
#pragma unroll
    for (int i = 0; i < 2; i++) {
      async_copy16(gA[i] + kt * 32, dstA[i]);
      async_copy16(gB[i] + kt * 32, dstB[i]);
    }
    __syncthreads();
    short8 a[4], b[4];
#pragma unroll
    for (int i = 0; i < 4; i++) { a[i] = *aptr[i]; b[i] = *bptr[i]; }
#pragma unroll
    for (int im = 0; im < 4; im++)
#pragma unroll
      for (int in = 0; in < 4; in++)
        acc[im][in] = __builtin_amdgcn_mfma_f32_16x16x32_bf16(a[im], b[in], acc[im][in], 0, 0, 0);
    __syncthreads();
  }

  // epilogue: C/D layout row=(lane>>4)*4+r, col=lane&15 (m89/m91-verified)
  const int Mv = cntE - mtile * 128;
#pragma unroll
  for (int im = 0; im < 4; im++) {
#pragma unroll
    for (int r = 0; r < 4; r++) {
      const int rl = wm + im * 16 + (lane >> 4) * 4 + r;
      if (rl < Mv) {
        const int pr = m0 + mtile * 128 + rl;
        if (MODE == 0) {
#pragma unroll
          for (int in = 0; in < 4; in++) {
            float v = acc[im][in][r];
            v = v > 0.f ? v * v : 0.f;   // relu^2
            const int col = ntile * 128 + wn + in * 16 + (lane & 15);
            hbuf[(size_t)pr * HDIM + col] = f2bf(v);
          }
        } else {
          const int tok = pairtok[pr];
          const float wgt = pairw[pr];
          float* orow = out + (size_t)tok * DDIM;
#pragma unroll
          for (int in = 0; in < 4; in++) {
            const int col = ntile * 128 + wn + in * 16 + (lane & 15);
            atomicAdd(orow + col, wgt * acc[im][in][r]);
          }
        }
      }
    }
  }
}

extern "C" void kernel_launch(void* const* d_in, const int* in_sizes, int n_in,
                              void* d_out, int out_size, void* d_ws, size_t ws_size,
                              hipStream_t stream) {
  const float* x   = (const float*)d_in[0];
  const float* gw  = (const float*)d_in[1];
  const float* wfc = (const float*)d_in[2];
  const float* wpj = (const float*)d_in[3];
  float* out = (float*)d_out;

  char* ws = (char*)d_ws;
  size_t off = 0;
  auto alloc = [&](size_t bytes) -> void* {
    void* p = ws + off;
    off += (bytes + 255) & ~(size_t)255;
    return p;
  };
  unsigned short* xb   = (unsigned short*)alloc((size_t)NTOK * DDIM * 2);
  unsigned short* wfcb = (unsigned short*)alloc((size_t)NEXP * HDIM * DDIM * 2);
  unsigned short* wpjb = (unsigned short*)alloc((size_t)NEXP * DDIM * HDIM * 2);
  unsigned short* hbuf = (unsigned short*)alloc((size_t)NPAIR * HDIM * 2);
  int*   pairtok = (int*)alloc(NPAIR * 4);
  float* pairw   = (float*)alloc(NPAIR * 4);
  int*   selE    = (int*)alloc(NTOK * 2 * 4);
  float* selW    = (float*)alloc(NTOK * 2 * 4);
  int*   ctr     = (int*)alloc(256);
  int* cnt = ctr; int* fill = ctr + 8; int* basep = ctr + 16;
  float* psum = (float*)(ctr + 32);

  hipMemsetAsync(ctr, 0, 256, stream);
  hipMemsetAsync(d_out, 0, (size_t)out_size * sizeof(float), stream);

  cast_kernel<<<(NTOK * DDIM / 4 + 255) / 256, 256, 0, stream>>>(x, xb, NTOK * DDIM / 4);
  cast_kernel<<<(NEXP * HDIM * DDIM / 4 + 255) / 256, 256, 0, stream>>>(wfc, wfcb, NEXP * HDIM * DDIM / 4);
  cast_kernel<<<(NEXP * DDIM * HDIM / 4 + 255) / 256, 256, 0, stream>>>(wpj, wpjb, NEXP * DDIM * HDIM / 4);

  gating_kernel<<<NTOK / 4, 256, 0, stream>>>(x, gw, selE, selW, cnt, psum);
  finalize_kernel<<<1, 1, 0, stream>>>(cnt, psum, basep, fill, out + (size_t)NTOK * DDIM);
  scatter_kernel<<<NTOK / 256, 256, 0, stream>>>(selE, selW, fill, pairtok, pairw);

  moe_gemm<DDIM, HDIM, 0><<<dim3(64, HDIM / 128, NEXP), 256, 0, stream>>>(
      xb, wfcb, basep, pairtok, pairw, hbuf, nullptr);
  moe_gemm<HDIM, DDIM, 1><<<dim3(64, DDIM / 128, NEXP), 256, 0, stream>>>(
      hbuf, wpjb, basep, pairtok, pairw, nullptr, out);
}

// Round 2
// 1100.676 us; speedup vs baseline: 1.0084x; 1.0084x over previous
//
#include <hip/hip_runtime.h>
#include <hip/hip_bf16.h>

#define NTOK 8192
#define DDIM 1024
#define HDIM 4096
#define NEXP 8
#define NPAIR (NTOK * 2)

typedef __attribute__((ext_vector_type(8))) short short8;
typedef __attribute__((ext_vector_type(4))) float floatx4;

__device__ __forceinline__ unsigned short f2bf(float f) {
  unsigned u = __float_as_uint(f);
  u += 0x7fffu + ((u >> 16) & 1u);   // RNE
  return (unsigned short)(u >> 16);
}

__device__ __forceinline__ void async_copy16(const void* g, void* l) {
  __builtin_amdgcn_global_load_lds(
      (const __attribute__((address_space(1))) unsigned int*)g,
      (__attribute__((address_space(3))) unsigned int*)l, 16, 0, 0);
}

// ---------------- cast f32 -> bf16, float4 vectorized ----------------
__global__ void cast_kernel(const float* __restrict__ src,
                            unsigned short* __restrict__ dst, int n4) {
  int i = blockIdx.x * 256 + threadIdx.x;
  if (i >= n4) return;
  const float4 v = ((const float4*)src)[i];
  ushort4 o;
  o.x = f2bf(v.x); o.y = f2bf(v.y); o.z = f2bf(v.z); o.w = f2bf(v.w);
  ((ushort4*)dst)[i] = o;
}

// ---------------- gating: 1 wave per token, fp64 accumulation ----------------
__global__ __launch_bounds__(256) void gating_kernel(
    const float* __restrict__ x, const float* __restrict__ gw,
    int* __restrict__ selE, float* __restrict__ selW,
    int* __restrict__ cnt, float* __restrict__ psum) {
  __shared__ float gws[NEXP * DDIM];      // 32 KB
  __shared__ float pblk[4][NEXP];
  __shared__ int cblk[NEXP];
  const int t = threadIdx.x;
  for (int i = t; i < NEXP * DDIM; i += 256) gws[i] = gw[i];
  if (t < NEXP) cblk[t] = 0;
  __syncthreads();
  const int wv = t >> 6, lane = t & 63;
  const int tok = blockIdx.x * 4 + wv;
  double acc[NEXP];
#pragma unroll
  for (int e = 0; e < NEXP; e++) acc[e] = 0.0;
  const float* xr = x + (size_t)tok * DDIM;
  for (int i = lane; i < DDIM; i += 64) {
    double xv = (double)xr[i];
#pragma unroll
    for (int e = 0; e < NEXP; e++) acc[e] += xv * (double)gws[e * DDIM + i];
  }
#pragma unroll
  for (int e = 0; e < NEXP; e++)
    for (int off = 32; off > 0; off >>= 1) acc[e] += __shfl_xor(acc[e], off, 64);
  if (lane == 0) {
    double mx = acc[0];
    for (int e = 1; e < NEXP; e++) mx = acc[e] > mx ? acc[e] : mx;
    double p[NEXP], s = 0.0;
    for (int e = 0; e < NEXP; e++) { p[e] = exp(acc[e] - mx); s += p[e]; }
    int e1 = 0; double b1 = p[0];
    for (int e = 1; e < NEXP; e++) if (p[e] > b1) { b1 = p[e]; e1 = e; }
    int e2 = -1; double b2 = -1.0;
    for (int e = 0; e < NEXP; e++) if (e != e1 && p[e] > b2) { b2 = p[e]; e2 = e; }
    double rs = b1 + b2;
    selE[tok * 2 + 0] = e1; selE[tok * 2 + 1] = e2;
    selW[tok * 2 + 0] = (float)(b1 / rs); selW[tok * 2 + 1] = (float)(b2 / rs);
    atomicAdd(&cblk[e1], 1); atomicAdd(&cblk[e2], 1);
    for (int e = 0; e < NEXP; e++) pblk[wv][e] = (float)(p[e] / s);
  }
  __syncthreads();
  if (t < NEXP) {
    float sp = pblk[0][t] + pblk[1][t] + pblk[2][t] + pblk[3][t];
    atomicAdd(&psum[t], sp);
    if (cblk[t]) atomicAdd(&cnt[t], cblk[t]);
  }
}

// ---------------- prefix sum over 8 experts + balance loss ----------------
__global__ void finalize_kernel(const int* __restrict__ cnt,
                                const float* __restrict__ psum,
                                int* __restrict__ base, int* __restrict__ fill,
                                float* __restrict__ loss_out) {
  int b = 0;
  for (int e = 0; e < NEXP; e++) { base[e] = b; fill[e] = b; b += cnt[e]; }
  base[NEXP] = b;
  double L = 0.0;
  for (int e = 0; e < NEXP; e++) L += (double)psum[e] * (double)cnt[e];
  *loss_out = (float)(L * (double)NEXP / ((double)NTOK * (double)NTOK));
}

// ---------------- scatter pairs + inverse map (token -> its 2 pair slots) ----------------
__global__ void scatter_kernel(const int* __restrict__ selE,
                               const float* __restrict__ selW,
                               int* __restrict__ fill, int* __restrict__ pairtok,
                               float* __restrict__ pairw, int* __restrict__ invmap) {
  int n = blockIdx.x * 256 + threadIdx.x;
  if (n >= NTOK) return;
  for (int k = 0; k < 2; k++) {
    int e = selE[n * 2 + k];
    int pos = atomicAdd(&fill[e], 1);
    pairtok[pos] = n;
    pairw[pos] = selW[n * 2 + k];
    invmap[n * 2 + k] = pos;
  }
}

// ---------------- combine: out[tok] = ybuf[p1] + ybuf[p2]  (weights pre-applied) ----------------
__global__ __launch_bounds__(256) void combine_kernel(
    const float* __restrict__ ybuf, const int* __restrict__ invmap,
    float* __restrict__ out) {
  const int tok = blockIdx.x;
  const int c = threadIdx.x;                    // float4 lane within row
  const int p1 = invmap[tok * 2 + 0];
  const int p2 = invmap[tok * 2 + 1];
  const float4 a = ((const float4*)(ybuf + (size_t)p1 * DDIM))[c];
  const float4 b = ((const float4*)(ybuf + (size_t)p2 * DDIM))[c];
  float4 o;
  o.x = a.x + b.x; o.y = a.y + b.y; o.z = a.z + b.z; o.w = a.w + b.w;
  ((float4*)(out + (size_t)tok * DDIM))[c] = o;
}

// ---------------- MFMA GEMM, NT layout (A [M][K], B [N][K] both K-major) ----------------
// MODE 0: FC1  A = xb gathered via pairtok, epilogue relu^2 -> hbuf bf16
// MODE 1: FC2  A = hbuf compact rows,       epilogue plain store w*y -> ybuf fp32
template <int KD, int ND, int MODE>
__global__ __launch_bounds__(256) void moe_gemm(
    const unsigned short* __restrict__ A, const unsigned short* __restrict__ B,
    const int* __restrict__ base, const int* __restrict__ pairtok,
    const float* __restrict__ pairw, unsigned short* __restrict__ hbuf,
    float* __restrict__ ybuf) {
  const int e = blockIdx.z;
  const int m0 = base[e], m1 = base[e + 1];
  const int cntE = m1 - m0;
  const int mtile = blockIdx.x;
  if (mtile * 128 >= cntE) return;
  const int ntile = blockIdx.y;

  __shared__ unsigned short ldsA[512 * 8];   // 128 x 32 bf16, 16B-chunk xor-swizzled
  __shared__ unsigned short ldsB[512 * 8];

  const int t = threadIdx.x, w = t >> 6, lane = t & 63;

  // staging: chunk c = wavebase + lane; chunk holds (row=c>>2, q=(c&3)^swz(row))
  const unsigned short* gA[2];
  const unsigned short* gB[2];
  unsigned short* dstA[2];
  unsigned short* dstB[2];
#pragma unroll
  for (int i = 0; i < 2; i++) {
    const int c = w * 128 + i * 64 + lane;
    const int row = c >> 2;
    const int q = (c & 3) ^ (row & 3) ^ ((row >> 2) & 3);
    dstA[i] = ldsA + (w * 128 + i * 64) * 8;   // wave-uniform LDS base
    dstB[i] = ldsB + (w * 128 + i * 64) * 8;
    int ar = mtile * 128 + row;
    if (ar > cntE - 1) ar = cntE - 1;          // clamp tail rows
    size_t arow;
    if (MODE == 0) arow = (size_t)pairtok[m0 + ar];
    else           arow = (size_t)(m0 + ar);
    gA[i] = A + arow * (size_t)KD + q * 8;
    gB[i] = B + ((size_t)e * ND + (ntile * 128 + row)) * (size_t)KD + q * 8;
  }

  // fragment read addresses (fixed across K loop)
  const int wm = (w & 1) * 64, wn = (w >> 1) * 64;
  const int sw = (lane >> 4) ^ (lane & 3) ^ ((lane >> 2) & 3);
  const short8* aptr[4];
  const short8* bptr[4];
#pragma unroll
  for (int i = 0; i < 4; i++) {
    aptr[i] = (const short8*)ldsA + (wm + i * 16 + (lane & 15)) * 4 + sw;
    bptr[i] = (const short8*)ldsB + (wn + i * 16 + (lane & 15)) * 4 + sw;
  }

  floatx4 acc[4][4] = {};

  for (int kt = 0; kt < KD / 32; kt++) {
#pragma unroll
    for (int i = 0; i < 2; i++) {
      async_copy16(gA[i] + kt * 32, dstA[i]);
      async_copy16(gB[i] + kt * 32, dstB[i]);
    }
    __syncthreads();
    short8 a[4], b[4];
#pragma unroll
    for (int i = 0; i < 4; i++) { a[i] = *aptr[i]; b[i] = *bptr[i]; }
#pragma unroll
    for (int im = 0; im < 4; im++)
#pragma unroll
      for (int in = 0; in < 4; in++)
        acc[im][in] = __builtin_amdgcn_mfma_f32_16x16x32_bf16(a[im], b[in], acc[im][in], 0, 0, 0);
    __syncthreads();
  }

  // epilogue: C/D layout row=(lane>>4)*4+r, col=lane&15 (m89/m91-verified)
  const int Mv = cntE - mtile * 128;
#pragma unroll
  for (int im = 0; im < 4; im++) {
#pragma unroll
    for (int r = 0; r < 4; r++) {
      const int rl = wm + im * 16 + (lane >> 4) * 4 + r;
      if (rl < Mv) {
        const int pr = m0 + mtile * 128 + rl;
        if (MODE == 0) {
#pragma unroll
          for (int in = 0; in < 4; in++) {
            float v = acc[im][in][r];
            v = v > 0.f ? v * v : 0.f;   // relu^2
            const int col = ntile * 128 + wn + in * 16 + (lane & 15);
            hbuf[(size_t)pr * HDIM + col] = f2bf(v);
          }
        } else {
          const float wgt = pairw[pr];
          float* yrow = ybuf + (size_t)pr * DDIM;
#pragma unroll
          for (int in = 0; in < 4; in++) {
            const int col = ntile * 128 + wn + in * 16 + (lane & 15);
            yrow[col] = wgt * acc[im][in][r];
          }
        }
      }
    }
  }
}

extern "C" void kernel_launch(void* const* d_in, const int* in_sizes, int n_in,
                              void* d_out, int out_size, void* d_ws, size_t ws_size,
                              hipStream_t stream) {
  const float* x   = (const float*)d_in[0];
  const float* gw  = (const float*)d_in[1];
  const float* wfc = (const float*)d_in[2];
  const float* wpj = (const float*)d_in[3];
  float* out = (float*)d_out;

  char* ws = (char*)d_ws;
  size_t off = 0;
  auto alloc = [&](size_t bytes) -> void* {
    void* p = ws + off;
    off += (bytes + 255) & ~(size_t)255;
    return p;
  };
  unsigned short* xb   = (unsigned short*)alloc((size_t)NTOK * DDIM * 2);
  unsigned short* wfcb = (unsigned short*)alloc((size_t)NEXP * HDIM * DDIM * 2);
  unsigned short* wpjb = (unsigned short*)alloc((size_t)NEXP * DDIM * HDIM * 2);
  unsigned short* hbuf = (unsigned short*)alloc((size_t)NPAIR * HDIM * 2);
  float* ybuf          = (float*)alloc((size_t)NPAIR * DDIM * 4);
  int*   pairtok = (int*)alloc(NPAIR * 4);
  float* pairw   = (float*)alloc(NPAIR * 4);
  int*   invmap  = (int*)alloc(NPAIR * 4);
  int*   selE    = (int*)alloc(NTOK * 2 * 4);
  float* selW    = (float*)alloc(NTOK * 2 * 4);
  int*   ctr     = (int*)alloc(256);
  int* cnt = ctr; int* fill = ctr + 8; int* basep = ctr + 16;
  float* psum = (float*)(ctr + 32);

  hipMemsetAsync(ctr, 0, 256, stream);

  cast_kernel<<<(NTOK * DDIM / 4 + 255) / 256, 256, 0, stream>>>(x, xb, NTOK * DDIM / 4);
  cast_kernel<<<(NEXP * HDIM * DDIM / 4 + 255) / 256, 256, 0, stream>>>(wfc, wfcb, NEXP * HDIM * DDIM / 4);
  cast_kernel<<<(NEXP * DDIM * HDIM / 4 + 255) / 256, 256, 0, stream>>>(wpj, wpjb, NEXP * DDIM * HDIM / 4);

  gating_kernel<<<NTOK / 4, 256, 0, stream>>>(x, gw, selE, selW, cnt, psum);
  finalize_kernel<<<1, 1, 0, stream>>>(cnt, psum, basep, fill, out + (size_t)NTOK * DDIM);
  scatter_kernel<<<NTOK / 256, 256, 0, stream>>>(selE, selW, fill, pairtok, pairw, invmap);

  moe_gemm<DDIM, HDIM, 0><<<dim3(64, HDIM / 128, NEXP), 256, 0, stream>>>(
      xb, wfcb, basep, pairtok, pairw, hbuf, nullptr);
  moe_gemm<HDIM, DDIM, 1><<<dim3(64, DDIM / 128, NEXP), 256, 0, stream>>>(
      hbuf, wpjb, basep, pairtok, pairw, nullptr, ybuf);

  combine_kernel<<<NTOK, 256, 0, stream>>>(ybuf, invmap, out);
}

// Round 3
// 913.302 us; speedup vs baseline: 1.2153x; 1.2052x over previous
//
#include <hip/hip_runtime.h>
#include <hip/hip_bf16.h>

#define NTOK 8192
#define DDIM 1024
#define HDIM 4096
#define NEXP 8
#define NPAIR (NTOK * 2)
#define NMTILE 136          // 16384/128 + up to 8 per-expert pad tiles
#define NPADROW (NPAIR + NEXP * 128)

typedef __attribute__((ext_vector_type(8))) short short8;
typedef __attribute__((ext_vector_type(4))) float floatx4;

__device__ __forceinline__ unsigned short f2bf(float f) {
  unsigned u = __float_as_uint(f);
  u += 0x7fffu + ((u >> 16) & 1u);   // RNE
  return (unsigned short)(u >> 16);
}

__device__ __forceinline__ void async_copy16(const void* g, void* l) {
  __builtin_amdgcn_global_load_lds(
      (const __attribute__((address_space(1))) unsigned int*)g,
      (__attribute__((address_space(3))) unsigned int*)l, 16, 0, 0);
}

// ---------------- cast f32 -> bf16, float4 vectorized ----------------
__global__ void cast_kernel(const float* __restrict__ src,
                            unsigned short* __restrict__ dst, int n4) {
  int i = blockIdx.x * 256 + threadIdx.x;
  if (i >= n4) return;
  const float4 v = ((const float4*)src)[i];
  ushort4 o;
  o.x = f2bf(v.x); o.y = f2bf(v.y); o.z = f2bf(v.z); o.w = f2bf(v.w);
  ((ushort4*)dst)[i] = o;
}

// ---------------- gating: 1 wave per token, fp64 accumulation ----------------
__global__ __launch_bounds__(256) void gating_kernel(
    const float* __restrict__ x, const float* __restrict__ gw,
    int* __restrict__ selE, float* __restrict__ selW,
    int* __restrict__ cnt, float* __restrict__ psum) {
  __shared__ float gws[NEXP * DDIM];      // 32 KB
  __shared__ float pblk[4][NEXP];
  __shared__ int cblk[NEXP];
  const int t = threadIdx.x;
  for (int i = t; i < NEXP * DDIM; i += 256) gws[i] = gw[i];
  if (t < NEXP) cblk[t] = 0;
  __syncthreads();
  const int wv = t >> 6, lane = t & 63;
  const int tok = blockIdx.x * 4 + wv;
  double acc[NEXP];
#pragma unroll
  for (int e = 0; e < NEXP; e++) acc[e] = 0.0;
  const float* xr = x + (size_t)tok * DDIM;
  for (int i = lane; i < DDIM; i += 64) {
    double xv = (double)xr[i];
#pragma unroll
    for (int e = 0; e < NEXP; e++) acc[e] += xv * (double)gws[e * DDIM + i];
  }
#pragma unroll
  for (int e = 0; e < NEXP; e++)
    for (int off = 32; off > 0; off >>= 1) acc[e] += __shfl_xor(acc[e], off, 64);
  if (lane == 0) {
    double mx = acc[0];
    for (int e = 1; e < NEXP; e++) mx = acc[e] > mx ? acc[e] : mx;
    double p[NEXP], s = 0.0;
    for (int e = 0; e < NEXP; e++) { p[e] = exp(acc[e] - mx); s += p[e]; }
    int e1 = 0; double b1 = p[0];
    for (int e = 1; e < NEXP; e++) if (p[e] > b1) { b1 = p[e]; e1 = e; }
    int e2 = -1; double b2 = -1.0;
    for (int e = 0; e < NEXP; e++) if (e != e1 && p[e] > b2) { b2 = p[e]; e2 = e; }
    double rs = b1 + b2;
    selE[tok * 2 + 0] = e1; selE[tok * 2 + 1] = e2;
    selW[tok * 2 + 0] = (float)(b1 / rs); selW[tok * 2 + 1] = (float)(b2 / rs);
    atomicAdd(&cblk[e1], 1); atomicAdd(&cblk[e2], 1);
    for (int e = 0; e < NEXP; e++) pblk[wv][e] = (float)(p[e] / s);
  }
  __syncthreads();
  if (t < NEXP) {
    float sp = pblk[0][t] + pblk[1][t] + pblk[2][t] + pblk[3][t];
    atomicAdd(&psum[t], sp);
    if (cblk[t]) atomicAdd(&cnt[t], cblk[t]);
  }
}

// ---------------- prefix sums (128-aligned) + tile->expert table + balance loss ----------------
__global__ void finalize_kernel(const int* __restrict__ cnt,
                                const float* __restrict__ psum,
                                int* __restrict__ abase, int* __restrict__ fill,
                                int* __restrict__ tile2exp,
                                float* __restrict__ loss_out) {
  for (int t = 0; t < NMTILE; t++) tile2exp[t] = -1;
  int b = 0;
  for (int e = 0; e < NEXP; e++) {
    abase[e] = b;
    fill[e] = b;
    int nt = (cnt[e] + 127) >> 7;
    for (int j = 0; j < nt; j++) tile2exp[(b >> 7) + j] = e;
    b += nt << 7;                       // pad region to multiple of 128
  }
  abase[NEXP] = b;
  double L = 0.0;
  for (int e = 0; e < NEXP; e++) L += (double)psum[e] * (double)cnt[e];
  *loss_out = (float)(L * (double)NEXP / ((double)NTOK * (double)NTOK));
}

// ---------------- scatter pairs + inverse map (token -> its 2 pair slots) ----------------
__global__ void scatter_kernel(const int* __restrict__ selE,
                               const float* __restrict__ selW,
                               int* __restrict__ fill, int* __restrict__ pairtok,
                               float* __restrict__ pairw, int* __restrict__ invmap) {
  int n = blockIdx.x * 256 + threadIdx.x;
  if (n >= NTOK) return;
  for (int k = 0; k < 2; k++) {
    int e = selE[n * 2 + k];
    int pos = atomicAdd(&fill[e], 1);
    pairtok[pos] = n;
    pairw[pos] = selW[n * 2 + k];
    invmap[n * 2 + k] = pos;
  }
}

// ---------------- combine: out[tok] = ybuf[p1] + ybuf[p2]  (weights pre-applied) ----------------
__global__ __launch_bounds__(256) void combine_kernel(
    const float* __restrict__ ybuf, const int* __restrict__ invmap,
    float* __restrict__ out) {
  const int tok = blockIdx.x;
  const int c = threadIdx.x;                    // float4 lane within row
  const int p1 = invmap[tok * 2 + 0];
  const int p2 = invmap[tok * 2 + 1];
  const float4 a = ((const float4*)(ybuf + (size_t)p1 * DDIM))[c];
  const float4 b = ((const float4*)(ybuf + (size_t)p2 * DDIM))[c];
  float4 o;
  o.x = a.x + b.x; o.y = a.y + b.y; o.z = a.z + b.z; o.w = a.w + b.w;
  ((float4*)(out + (size_t)tok * DDIM))[c] = o;
}

// ---------------- MFMA GEMM, NT layout (A [M][K], B [N][K] both K-major) ----------------
// Grid: x = global mtile (dense, via tile2exp), y = ntile. No dead-block resonance.
// MODE 0: FC1  A = xb gathered via pairtok, epilogue relu^2 -> hbuf bf16
// MODE 1: FC2  A = hbuf padded-compact rows, epilogue plain store w*y -> ybuf fp32
template <int KD, int ND, int MODE>
__global__ __launch_bounds__(256) void moe_gemm(
    const unsigned short* __restrict__ A, const unsigned short* __restrict__ B,
    const int* __restrict__ abase, const int* __restrict__ cnt,
    const int* __restrict__ tile2exp, const int* __restrict__ pairtok,
    const float* __restrict__ pairw, unsigned short* __restrict__ hbuf,
    float* __restrict__ ybuf) {
  const int mtile = blockIdx.x;
  const int e = tile2exp[mtile];
  if (e < 0) return;                          // <=8 pad tiles total
  const int m0 = abase[e];                    // 128-aligned padded base
  const int cntE = cnt[e];                    // live rows for this expert
  const int mloc = mtile * 128 - m0;          // local row offset within expert
  const int ntile = blockIdx.y;

  __shared__ unsigned short ldsA[512 * 8];   // 128 x 32 bf16, 16B-chunk xor-swizzled
  __shared__ unsigned short ldsB[512 * 8];

  const int t = threadIdx.x, w = t >> 6, lane = t & 63;

  // staging: chunk c = wavebase + lane; chunk holds (row=c>>2, q=(c&3)^swz(row))
  const unsigned short* gA[2];
  const unsigned short* gB[2];
  unsigned short* dstA[2];
  unsigned short* dstB[2];
#pragma unroll
  for (int i = 0; i < 2; i++) {
    const int c = w * 128 + i * 64 + lane;
    const int row = c >> 2;
    const int q = (c & 3) ^ (row & 3) ^ ((row >> 2) & 3);
    dstA[i] = ldsA + (w * 128 + i * 64) * 8;   // wave-uniform LDS base
    dstB[i] = ldsB + (w * 128 + i * 64) * 8;
    int ar = mloc + row;
    if (ar > cntE - 1) ar = cntE - 1;          // clamp tail rows
    size_t arow;
    if (MODE == 0) arow = (size_t)pairtok[m0 + ar];
    else           arow = (size_t)(m0 + ar);
    gA[i] = A + arow * (size_t)KD + q * 8;
    gB[i] = B + ((size_t)e * ND + (ntile * 128 + row)) * (size_t)KD + q * 8;
  }

  // fragment read addresses (fixed across K loop)
  const int wm = (w & 1) * 64, wn = (w >> 1) * 64;
  const int sw = (lane >> 4) ^ (lane & 3) ^ ((lane >> 2) & 3);
  const short8* aptr[4];
  const short8* bptr[4];
#pragma unroll
  for (int i = 0; i < 4; i++) {
    aptr[i] = (const short8*)ldsA + (wm + i * 16 + (lane & 15)) * 4 + sw;
    bptr[i] = (const short8*)ldsB + (wn + i * 16 + (lane & 15)) * 4 + sw;
  }

  floatx4 acc[4][4] = {};

  for (int kt = 0; kt < KD / 32; kt++) {
#pragma unroll
    for (int i = 0; i < 2; i++) {
      async_copy16(gA[i] + kt * 32, dstA[i]);
      async_copy16(gB[i] + kt * 32, dstB[i]);
    }
    __syncthreads();
    short8 a[4], b[4];
#pragma unroll
    for (int i = 0; i < 4; i++) { a[i] = *aptr[i]; b[i] = *bptr[i]; }
#pragma unroll
    for (int im = 0; im < 4; im++)
#pragma unroll
      for (int in = 0; in < 4; in++)
        acc[im][in] = __builtin_amdgcn_mfma_f32_16x16x32_bf16(a[im], b[in], acc[im][in], 0, 0, 0);
    __syncthreads();
  }

  // epilogue: C/D layout row=(lane>>4)*4+r, col=lane&15 (m89/m91-verified)
  const int Mv = cntE - mloc;                  // may exceed 128; rl < 128 anyway
#pragma unroll
  for (int im = 0; im < 4; im++) {
#pragma unroll
    for (int r = 0; r < 4; r++) {
      const int rl = wm + im * 16 + (lane >> 4) * 4 + r;
      if (rl < Mv) {
        const int pr = m0 + mloc + rl;
        if (MODE == 0) {
#pragma unroll
          for (int in = 0; in < 4; in++) {
            float v = acc[im][in][r];
            v = v > 0.f ? v * v : 0.f;   // relu^2
            const int col = ntile * 128 + wn + in * 16 + (lane & 15);
            hbuf[(size_t)pr * HDIM + col] = f2bf(v);
          }
        } else {
          const float wgt = pairw[pr];
          float* yrow = ybuf + (size_t)pr * DDIM;
#pragma unroll
          for (int in = 0; in < 4; in++) {
            const int col = ntile * 128 + wn + in * 16 + (lane & 15);
            yrow[col] = wgt * acc[im][in][r];
          }
        }
      }
    }
  }
}

extern "C" void kernel_launch(void* const* d_in, const int* in_sizes, int n_in,
                              void* d_out, int out_size, void* d_ws, size_t ws_size,
                              hipStream_t stream) {
  const float* x   = (const float*)d_in[0];
  const float* gw  = (const float*)d_in[1];
  const float* wfc = (const float*)d_in[2];
  const float* wpj = (const float*)d_in[3];
  float* out = (float*)d_out;

  char* ws = (char*)d_ws;
  size_t off = 0;
  auto alloc = [&](size_t bytes) -> void* {
    void* p = ws + off;
    off += (bytes + 255) & ~(size_t)255;
    return p;
  };
  unsigned short* xb   = (unsigned short*)alloc((size_t)NTOK * DDIM * 2);
  unsigned short* wfcb = (unsigned short*)alloc((size_t)NEXP * HDIM * DDIM * 2);
  unsigned short* wpjb = (unsigned short*)alloc((size_t)NEXP * DDIM * HDIM * 2);
  unsigned short* hbuf = (unsigned short*)alloc((size_t)NPADROW * HDIM * 2);
  float* ybuf          = (float*)alloc((size_t)NPADROW * DDIM * 4);
  int*   pairtok = (int*)alloc(NPADROW * 4);
  float* pairw   = (float*)alloc(NPADROW * 4);
  int*   invmap  = (int*)alloc(NPAIR * 4);
  int*   selE    = (int*)alloc(NTOK * 2 * 4);
  float* selW    = (float*)alloc(NTOK * 2 * 4);
  int*   ctr     = (int*)alloc(1024);
  int* cnt = ctr; int* fill = ctr + 8; int* abase = ctr + 16;   // abase: 9 ints
  float* psum = (float*)(ctr + 28);                              // 8 floats
  int* tile2exp = ctr + 40;                                      // 136 ints

  hipMemsetAsync(ctr, 0, 1024, stream);

  cast_kernel<<<(NTOK * DDIM / 4 + 255) / 256, 256, 0, stream>>>(x, xb, NTOK * DDIM / 4);
  cast_kernel<<<(NEXP * HDIM * DDIM / 4 + 255) / 256, 256, 0, stream>>>(wfc, wfcb, NEXP * HDIM * DDIM / 4);
  cast_kernel<<<(NEXP * DDIM * HDIM / 4 + 255) / 256, 256, 0, stream>>>(wpj, wpjb, NEXP * DDIM * HDIM / 4);

  gating_kernel<<<NTOK / 4, 256, 0, stream>>>(x, gw, selE, selW, cnt, psum);
  finalize_kernel<<<1, 1, 0, stream>>>(cnt, psum, abase, fill, tile2exp,
                                       out + (size_t)NTOK * DDIM);
  scatter_kernel<<<NTOK / 256, 256, 0, stream>>>(selE, selW, fill, pairtok, pairw, invmap);

  moe_gemm<DDIM, HDIM, 0><<<dim3(NMTILE, HDIM / 128), 256, 0, stream>>>(
      xb, wfcb, abase, cnt, tile2exp, pairtok, pairw, hbuf, nullptr);
  moe_gemm<HDIM, DDIM, 1><<<dim3(NMTILE, DDIM / 128), 256, 0, stream>>>(
      hbuf, wpjb, abase, cnt, tile2exp, pairtok, pairw, nullptr, ybuf);

  combine_kernel<<<NTOK, 256, 0, stream>>>(ybuf, invmap, out);
}

// Round 4
// 888.112 us; speedup vs baseline: 1.2498x; 1.0284x over previous
//
#include <hip/hip_runtime.h>
#include <hip/hip_bf16.h>

#define NTOK 8192
#define DDIM 1024
#define HDIM 4096
#define NEXP 8
#define NPAIR (NTOK * 2)
#define NMTILE 136          // 16384/128 + up to 8 per-expert pad tiles
#define NPADROW (NPAIR + NEXP * 128)

typedef __attribute__((ext_vector_type(8))) short short8;
typedef __attribute__((ext_vector_type(4))) float floatx4;

__device__ __forceinline__ unsigned short f2bf(float f) {
  unsigned u = __float_as_uint(f);
  u += 0x7fffu + ((u >> 16) & 1u);   // RNE
  return (unsigned short)(u >> 16);
}

__device__ __forceinline__ void async_copy16(const void* g, void* l) {
  __builtin_amdgcn_global_load_lds(
      (const __attribute__((address_space(1))) unsigned int*)g,
      (__attribute__((address_space(3))) unsigned int*)l, 16, 0, 0);
}

// ---------------- cast f32 -> bf16, float4 vectorized ----------------
__global__ void cast_kernel(const float* __restrict__ src,
                            unsigned short* __restrict__ dst, int n4) {
  int i = blockIdx.x * 256 + threadIdx.x;
  if (i >= n4) return;
  const float4 v = ((const float4*)src)[i];
  ushort4 o;
  o.x = f2bf(v.x); o.y = f2bf(v.y); o.z = f2bf(v.z); o.w = f2bf(v.w);
  ((ushort4*)dst)[i] = o;
}

// ---------------- gating: 1 wave per token, fp64 accumulation ----------------
__global__ __launch_bounds__(256) void gating_kernel(
    const float* __restrict__ x, const float* __restrict__ gw,
    int* __restrict__ selE, float* __restrict__ selW,
    int* __restrict__ cnt, float* __restrict__ psum) {
  __shared__ float gws[NEXP * DDIM];      // 32 KB
  __shared__ float pblk[4][NEXP];
  __shared__ int cblk[NEXP];
  const int t = threadIdx.x;
  for (int i = t; i < NEXP * DDIM; i += 256) gws[i] = gw[i];
  if (t < NEXP) cblk[t] = 0;
  __syncthreads();
  const int wv = t >> 6, lane = t & 63;
  const int tok = blockIdx.x * 4 + wv;
  double acc[NEXP];
#pragma unroll
  for (int e = 0; e < NEXP; e++) acc[e] = 0.0;
  const float* xr = x + (size_t)tok * DDIM;
  for (int i = lane; i < DDIM; i += 64) {
    double xv = (double)xr[i];
#pragma unroll
    for (int e = 0; e < NEXP; e++) acc[e] += xv * (double)gws[e * DDIM + i];
  }
#pragma unroll
  for (int e = 0; e < NEXP; e++)
    for (int off = 32; off > 0; off >>= 1) acc[e] += __shfl_xor(acc[e], off, 64);
  if (lane == 0) {
    double mx = acc[0];
    for (int e = 1; e < NEXP; e++) mx = acc[e] > mx ? acc[e] : mx;
    double p[NEXP], s = 0.0;
    for (int e = 0; e < NEXP; e++) { p[e] = exp(acc[e] - mx); s += p[e]; }
    int e1 = 0; double b1 = p[0];
    for (int e = 1; e < NEXP; e++) if (p[e] > b1) { b1 = p[e]; e1 = e; }
    int e2 = -1; double b2 = -1.0;
    for (int e = 0; e < NEXP; e++) if (e != e1 && p[e] > b2) { b2 = p[e]; e2 = e; }
    double rs = b1 + b2;
    selE[tok * 2 + 0] = e1; selE[tok * 2 + 1] = e2;
    selW[tok * 2 + 0] = (float)(b1 / rs); selW[tok * 2 + 1] = (float)(b2 / rs);
    atomicAdd(&cblk[e1], 1); atomicAdd(&cblk[e2], 1);
    for (int e = 0; e < NEXP; e++) pblk[wv][e] = (float)(p[e] / s);
  }
  __syncthreads();
  if (t < NEXP) {
    float sp = pblk[0][t] + pblk[1][t] + pblk[2][t] + pblk[3][t];
    atomicAdd(&psum[t], sp);
    if (cblk[t]) atomicAdd(&cnt[t], cblk[t]);
  }
}

// ---------------- prefix sums (128-aligned) + tile->expert table + balance loss ----------------
__global__ void finalize_kernel(const int* __restrict__ cnt,
                                const float* __restrict__ psum,
                                int* __restrict__ abase, int* __restrict__ fill,
                                int* __restrict__ tile2exp,
                                float* __restrict__ loss_out) {
  for (int t = 0; t < NMTILE; t++) tile2exp[t] = -1;
  int b = 0;
  for (int e = 0; e < NEXP; e++) {
    abase[e] = b;
    fill[e] = b;
    int nt = (cnt[e] + 127) >> 7;
    for (int j = 0; j < nt; j++) tile2exp[(b >> 7) + j] = e;
    b += nt << 7;                       // pad region to multiple of 128
  }
  abase[NEXP] = b;
  double L = 0.0;
  for (int e = 0; e < NEXP; e++) L += (double)psum[e] * (double)cnt[e];
  *loss_out = (float)(L * (double)NEXP / ((double)NTOK * (double)NTOK));
}

// ---------------- scatter pairs + inverse map (token -> its 2 pair slots) ----------------
__global__ void scatter_kernel(const int* __restrict__ selE,
                               const float* __restrict__ selW,
                               int* __restrict__ fill, int* __restrict__ pairtok,
                               float* __restrict__ pairw, int* __restrict__ invmap) {
  int n = blockIdx.x * 256 + threadIdx.x;
  if (n >= NTOK) return;
  for (int k = 0; k < 2; k++) {
    int e = selE[n * 2 + k];
    int pos = atomicAdd(&fill[e], 1);
    pairtok[pos] = n;
    pairw[pos] = selW[n * 2 + k];
    invmap[n * 2 + k] = pos;
  }
}

// ---------------- combine: out[tok] = ybuf[p1] + ybuf[p2]  (weights pre-applied) ----------------
__global__ __launch_bounds__(256) void combine_kernel(
    const float* __restrict__ ybuf, const int* __restrict__ invmap,
    float* __restrict__ out) {
  const int tok = blockIdx.x;
  const int c = threadIdx.x;                    // float4 lane within row
  const int p1 = invmap[tok * 2 + 0];
  const int p2 = invmap[tok * 2 + 1];
  const float4 a = ((const float4*)(ybuf + (size_t)p1 * DDIM))[c];
  const float4 b = ((const float4*)(ybuf + (size_t)p2 * DDIM))[c];
  float4 o;
  o.x = a.x + b.x; o.y = a.y + b.y; o.z = a.z + b.z; o.w = a.w + b.w;
  ((float4*)(out + (size_t)tok * DDIM))[c] = o;
}

// ---------------- MFMA GEMM, NT layout (A [M][K], B [N][K] both K-major) ----------------
// Grid: x = ntile (fast), y = global mtile. Consecutive blocks share the A-tile and
// sweep mtiles slowly -> A streams from HBM once, B + recent A stay L2/L3-hot.
// MODE 0: FC1  A = xb gathered via pairtok, epilogue relu^2 -> hbuf bf16
// MODE 1: FC2  A = hbuf padded-compact rows, epilogue plain store w*y -> ybuf fp32
template <int KD, int ND, int MODE>
__global__ __launch_bounds__(256) void moe_gemm(
    const unsigned short* __restrict__ A, const unsigned short* __restrict__ B,
    const int* __restrict__ abase, const int* __restrict__ cnt,
    const int* __restrict__ tile2exp, const int* __restrict__ pairtok,
    const float* __restrict__ pairw, unsigned short* __restrict__ hbuf,
    float* __restrict__ ybuf) {
  const int mtile = blockIdx.y;
  const int e = tile2exp[mtile];
  if (e < 0) return;                          // <=8 pad tiles total
  const int m0 = abase[e];                    // 128-aligned padded base
  const int cntE = cnt[e];                    // live rows for this expert
  const int mloc = mtile * 128 - m0;          // local row offset within expert
  const int ntile = blockIdx.x;

  __shared__ unsigned short ldsA[512 * 8];   // 128 x 32 bf16, 16B-chunk xor-swizzled
  __shared__ unsigned short ldsB[512 * 8];

  const int t = threadIdx.x, w = t >> 6, lane = t & 63;

  // staging: chunk c = wavebase + lane; chunk holds (row=c>>2, q=(c&3)^swz(row))
  const unsigned short* gA[2];
  const unsigned short* gB[2];
  unsigned short* dstA[2];
  unsigned short* dstB[2];
#pragma unroll
  for (int i = 0; i < 2; i++) {
    const int c = w * 128 + i * 64 + lane;
    const int row = c >> 2;
    const int q = (c & 3) ^ (row & 3) ^ ((row >> 2) & 3);
    dstA[i] = ldsA + (w * 128 + i * 64) * 8;   // wave-uniform LDS base
    dstB[i] = ldsB + (w * 128 + i * 64) * 8;
    int ar = mloc + row;
    if (ar > cntE - 1) ar = cntE - 1;          // clamp tail rows
    size_t arow;
    if (MODE == 0) arow = (size_t)pairtok[m0 + ar];
    else           arow = (size_t)(m0 + ar);
    gA[i] = A + arow * (size_t)KD + q * 8;
    gB[i] = B + ((size_t)e * ND + (ntile * 128 + row)) * (size_t)KD + q * 8;
  }

  // fragment read addresses (fixed across K loop)
  const int wm = (w & 1) * 64, wn = (w >> 1) * 64;
  const int sw = (lane >> 4) ^ (lane & 3) ^ ((lane >> 2) & 3);
  const short8* aptr[4];
  const short8* bptr[4];
#pragma unroll
  for (int i = 0; i < 4; i++) {
    aptr[i] = (const short8*)ldsA + (wm + i * 16 + (lane & 15)) * 4 + sw;
    bptr[i] = (const short8*)ldsB + (wn + i * 16 + (lane & 15)) * 4 + sw;
  }

  floatx4 acc[4][4] = {};

  for (int kt = 0; kt < KD / 32; kt++) {
#pragma unroll
    for (int i = 0; i < 2; i++) {
      async_copy16(gA[i] + kt * 32, dstA[i]);
      async_copy16(gB[i] + kt * 32, dstB[i]);
    }
    __syncthreads();
    short8 a[4], b[4];
#pragma unroll
    for (int i = 0; i < 4; i++) { a[i] = *aptr[i]; b[i] = *bptr[i]; }
#pragma unroll
    for (int im = 0; im < 4; im++)
#pragma unroll
      for (int in = 0; in < 4; in++)
        acc[im][in] = __builtin_amdgcn_mfma_f32_16x16x32_bf16(a[im], b[in], acc[im][in], 0, 0, 0);
    __syncthreads();
  }

  // epilogue: C/D layout row=(lane>>4)*4+r, col=lane&15 (m89/m91-verified)
  const int Mv = cntE - mloc;                  // may exceed 128; rl < 128 anyway
#pragma unroll
  for (int im = 0; im < 4; im++) {
#pragma unroll
    for (int r = 0; r < 4; r++) {
      const int rl = wm + im * 16 + (lane >> 4) * 4 + r;
      if (rl < Mv) {
        const int pr = m0 + mloc + rl;
        if (MODE == 0) {
#pragma unroll
          for (int in = 0; in < 4; in++) {
            float v = acc[im][in][r];
            v = v > 0.f ? v * v : 0.f;   // relu^2
            const int col = ntile * 128 + wn + in * 16 + (lane & 15);
            hbuf[(size_t)pr * HDIM + col] = f2bf(v);
          }
        } else {
          const float wgt = pairw[pr];
          float* yrow = ybuf + (size_t)pr * DDIM;
#pragma unroll
          for (int in = 0; in < 4; in++) {
            const int col = ntile * 128 + wn + in * 16 + (lane & 15);
            yrow[col] = wgt * acc[im][in][r];
          }
        }
      }
    }
  }
}

extern "C" void kernel_launch(void* const* d_in, const int* in_sizes, int n_in,
                              void* d_out, int out_size, void* d_ws, size_t ws_size,
                              hipStream_t stream) {
  const float* x   = (const float*)d_in[0];
  const float* gw  = (const float*)d_in[1];
  const float* wfc = (const float*)d_in[2];
  const float* wpj = (const float*)d_in[3];
  float* out = (float*)d_out;

  char* ws = (char*)d_ws;
  size_t off = 0;
  auto alloc = [&](size_t bytes) -> void* {
    void* p = ws + off;
    off += (bytes + 255) & ~(size_t)255;
    return p;
  };
  unsigned short* xb   = (unsigned short*)alloc((size_t)NTOK * DDIM * 2);
  unsigned short* wfcb = (unsigned short*)alloc((size_t)NEXP * HDIM * DDIM * 2);
  unsigned short* wpjb = (unsigned short*)alloc((size_t)NEXP * DDIM * HDIM * 2);
  unsigned short* hbuf = (unsigned short*)alloc((size_t)NPADROW * HDIM * 2);
  float* ybuf          = (float*)alloc((size_t)NPADROW * DDIM * 4);
  int*   pairtok = (int*)alloc(NPADROW * 4);
  float* pairw   = (float*)alloc(NPADROW * 4);
  int*   invmap  = (int*)alloc(NPAIR * 4);
  int*   selE    = (int*)alloc(NTOK * 2 * 4);
  float* selW    = (float*)alloc(NTOK * 2 * 4);
  int*   ctr     = (int*)alloc(1024);
  int* cnt = ctr; int* fill = ctr + 8; int* abase = ctr + 16;   // abase: 9 ints
  float* psum = (float*)(ctr + 28);                              // 8 floats
  int* tile2exp = ctr + 40;                                      // 136 ints

  hipMemsetAsync(ctr, 0, 1024, stream);

  cast_kernel<<<(NTOK * DDIM / 4 + 255) / 256, 256, 0, stream>>>(x, xb, NTOK * DDIM / 4);
  cast_kernel<<<(NEXP * HDIM * DDIM / 4 + 255) / 256, 256, 0, stream>>>(wfc, wfcb, NEXP * HDIM * DDIM / 4);
  cast_kernel<<<(NEXP * DDIM * HDIM / 4 + 255) / 256, 256, 0, stream>>>(wpj, wpjb, NEXP * DDIM * HDIM / 4);

  gating_kernel<<<NTOK / 4, 256, 0, stream>>>(x, gw, selE, selW, cnt, psum);
  finalize_kernel<<<1, 1, 0, stream>>>(cnt, psum, abase, fill, tile2exp,
                                       out + (size_t)NTOK * DDIM);
  scatter_kernel<<<NTOK / 256, 256, 0, stream>>>(selE, selW, fill, pairtok, pairw, invmap);

  moe_gemm<DDIM, HDIM, 0><<<dim3(HDIM / 128, NMTILE), 256, 0, stream>>>(
      xb, wfcb, abase, cnt, tile2exp, pairtok, pairw, hbuf, nullptr);
  moe_gemm<HDIM, DDIM, 1><<<dim3(DDIM / 128, NMTILE), 256, 0, stream>>>(
      hbuf, wpjb, abase, cnt, tile2exp, pairtok, pairw, nullptr, ybuf);

  combine_kernel<<<NTOK, 256, 0, stream>>>(ybuf, invmap, out);
}